// Round 20
// baseline (83.825 us; speedup 1.0000x reference)
//
#include <hip/hip_runtime.h>

typedef __attribute__((ext_vector_type(8))) short short8;
typedef __attribute__((ext_vector_type(4))) short short4v;
typedef __attribute__((ext_vector_type(4))) float f32x4;
typedef __attribute__((ext_vector_type(2))) unsigned int uint2v;

constexpr int SL = 2048, BS = 4, D = 512, H = 8, NH = 64;
constexpr int M_ROWS = SL * BS;   // 8192
constexpr float SCALE = 0.125f;   // 1/sqrt(64)
constexpr float LOG2E = 1.44269504088896340736f;

__device__ __forceinline__ unsigned short f2bf(float f) {
  union { float f; unsigned u; } v; v.f = f;
  unsigned r = v.u + 0x7FFFu + ((v.u >> 16) & 1u);
  return (unsigned short)(r >> 16);
}

__device__ __forceinline__ float bf2f(unsigned short s) {
  union { unsigned u; float f; } t; t.u = (unsigned)s << 16; return t.f;
}

__device__ __forceinline__ unsigned cvt_pk_bf16(float a, float b) {
  unsigned r;
  asm("v_cvt_pk_bf16_f32 %0, %1, %2" : "=v"(r) : "v"(a), "v"(b));
  return r;
}

__device__ __forceinline__ float fast_exp2(float x) {
  float r;
  asm("v_exp_f32 %0, %1" : "=v"(r) : "v"(x));
  return r;
}

// async global->LDS, 16B per lane; LDS dest = wave-uniform base + lane*16
__device__ __forceinline__ void gl16(const void* g, void* l) {
  __builtin_amdgcn_global_load_lds(
      (const __attribute__((address_space(1))) unsigned int*)g,
      (__attribute__((address_space(3))) unsigned int*)l, 16, 0, 0);
}

// ---------------------------------------------------------------------------
// prep: W[512][512] f32 row-major -> W^T[n][k] bf16, LDS-tiled 64x64.
// ---------------------------------------------------------------------------
__global__ __launch_bounds__(256) void prep_wt(
    const float* __restrict__ w0, const float* __restrict__ w1,
    const float* __restrict__ w2, const float* __restrict__ w3,
    unsigned short* __restrict__ wtb) {
  __shared__ float tl[64][65];
  const int tid = threadIdx.x;
  const int wi = blockIdx.x >> 6, t6 = blockIdx.x & 63;
  const int k0 = (t6 >> 3) * 64, n0 = (t6 & 7) * 64;
  const float* W = wi == 0 ? w0 : (wi == 1 ? w1 : (wi == 2 ? w2 : w3));
  unsigned short* WT = wtb + (size_t)wi * D * D;

#pragma unroll
  for (int i = 0; i < 4; ++i) {
    int k = (tid >> 4) + i * 16, n4 = (tid & 15) * 4;
    f32x4 v = *reinterpret_cast<const f32x4*>(&W[(size_t)(k0 + k) * D + n0 + n4]);
#pragma unroll
    for (int j = 0; j < 4; ++j) tl[n4 + j][k] = v[j];
  }
  __syncthreads();
#pragma unroll
  for (int i = 0; i < 2; ++i) {
    int n = (tid >> 3) + i * 32, k8 = (tid & 7) * 8;
    union { unsigned u[4]; short8 s; } pk;
#pragma unroll
    for (int j = 0; j < 4; ++j)
      pk.u[j] = cvt_pk_bf16(tl[n][k8 + 2 * j], tl[n][k8 + 2 * j + 1]);
    *reinterpret_cast<short8*>(&WT[(size_t)(n0 + n) * D + k0 + k8]) = pk.s;
  }
}

// ---------------------------------------------------------------------------
// GEMM v2 (round-19, unchanged): double-buffered 2-phase pipeline, counted
// vmcnt, XOR-swizzled LDS, XCD-affinity block remap by callers.
// ---------------------------------------------------------------------------
template <bool A_BF16, int OUT_MODE>
__device__ __forceinline__ void gemm_bt_body(const void* __restrict__ Ap,
                                             const unsigned short* __restrict__ BT,
                                             const float* __restrict__ bias,
                                             void* __restrict__ Outp, float scale,
                                             unsigned short* smem,
                                             int bx, int by) {
  const int tid = threadIdx.x;
  const int brow = bx * 128;
  const int bcol = by * 128;
  const int lane = tid & 63;
  const int wid = tid >> 6;
  const int wr = (wid >> 1) * 64;
  const int wc = (wid & 1) * 64;
  const int r = lane & 15;
  const int g = lane >> 4;

  auto a_buf = [&](int b) { return smem + b * 16384; };
  auto b_buf = [&](int b) { return smem + b * 16384 + 8192; };

  f32x4 acc[4][4];
#pragma unroll
  for (int m = 0; m < 4; ++m)
#pragma unroll
    for (int n = 0; n < 4; ++n) acc[m][n] = f32x4{0.f, 0.f, 0.f, 0.f};

  auto STAGE_B = [&](int kt, int bsel) {
    unsigned short* bl = b_buf(bsel);
#pragma unroll
    for (int j = 0; j < 4; ++j) {
      int c = j * 256 + tid;
      int row = c >> 3, c8 = (c & 7) ^ (row & 7);
      gl16(&BT[(size_t)(bcol + row) * D + kt + c8 * 8], &bl[c * 8]);
    }
  };
  auto STAGE_A_LDS = [&](int kt, int bsel) {
    const unsigned short* A = (const unsigned short*)Ap;
    unsigned short* al = a_buf(bsel);
#pragma unroll
    for (int j = 0; j < 4; ++j) {
      int c = j * 256 + tid;
      int row = c >> 3, c8 = (c & 7) ^ (row & 7);
      gl16(&A[(size_t)(brow + row) * D + kt + c8 * 8], &al[c * 8]);
    }
  };
  auto A_LOAD = [&](int kt, f32x4 (&va)[4][2]) {
    const float* A = (const float*)Ap;
#pragma unroll
    for (int j = 0; j < 4; ++j) {
      int c = j * 256 + tid;
      int row = c >> 3, c8 = (c & 7) ^ (row & 7);
      const float* ap = &A[(size_t)(brow + row) * D + kt + c8 * 8];
      va[j][0] = *reinterpret_cast<const f32x4*>(ap);
      va[j][1] = *reinterpret_cast<const f32x4*>(ap + 4);
    }
  };
  auto A_WRITE = [&](f32x4 (&va)[4][2], int bsel) {
    unsigned short* al = a_buf(bsel);
#pragma unroll
    for (int j = 0; j < 4; ++j) {
      int c = j * 256 + tid;
      union { unsigned u[4]; short8 s; } pk;
      pk.u[0] = cvt_pk_bf16(va[j][0][0], va[j][0][1]);
      pk.u[1] = cvt_pk_bf16(va[j][0][2], va[j][0][3]);
      pk.u[2] = cvt_pk_bf16(va[j][1][0], va[j][1][1]);
      pk.u[3] = cvt_pk_bf16(va[j][1][2], va[j][1][3]);
      *reinterpret_cast<short8*>(&al[c * 8]) = pk.s;
    }
  };
  auto COMPUTE = [&](int bsel) {
    const unsigned short* al = a_buf(bsel);
    const unsigned short* bl = b_buf(bsel);
#pragma unroll
    for (int kk2 = 0; kk2 < 2; ++kk2) {
      short8 af[4], bfr[4];
#pragma unroll
      for (int m = 0; m < 4; ++m)
        af[m] = *reinterpret_cast<const short8*>(
            &al[(wr + m * 16 + r) * 64 + (((kk2 * 4 + g) ^ (r & 7)) * 8)]);
#pragma unroll
      for (int n = 0; n < 4; ++n)
        bfr[n] = *reinterpret_cast<const short8*>(
            &bl[(wc + n * 16 + r) * 64 + (((kk2 * 4 + g) ^ (r & 7)) * 8)]);
      __builtin_amdgcn_s_setprio(1);
#pragma unroll
      for (int m = 0; m < 4; ++m)
#pragma unroll
        for (int n = 0; n < 4; ++n)
          acc[m][n] = __builtin_amdgcn_mfma_f32_16x16x32_bf16(af[m], bfr[n], acc[m][n], 0, 0, 0);
      __builtin_amdgcn_s_setprio(0);
    }
  };

  if (A_BF16) {
    STAGE_A_LDS(0, 0);
    STAGE_B(0, 0);
    asm volatile("s_waitcnt vmcnt(0)" ::: "memory");
  } else {
    f32x4 va[4][2];
    A_LOAD(0, va);
    STAGE_B(0, 0);
    asm volatile("s_waitcnt vmcnt(4)" ::: "memory");
    A_WRITE(va, 0);
    asm volatile("s_waitcnt vmcnt(0) lgkmcnt(0)" ::: "memory");
  }
  __builtin_amdgcn_s_barrier();

#pragma unroll
  for (int t = 0; t < 8; ++t) {
    const int cur = t & 1, nxt = cur ^ 1;
    const int ktn = (t + 1) * 64;
    __builtin_amdgcn_sched_barrier(0);
    f32x4 va[4][2];
    if (t < 7) {
      if (A_BF16) {
        STAGE_A_LDS(ktn, nxt);
        STAGE_B(ktn, nxt);
      } else {
        A_LOAD(ktn, va);
        STAGE_B(ktn, nxt);
      }
    }
    __builtin_amdgcn_sched_barrier(0);
    COMPUTE(cur);
    if (t < 7) {
      if (!A_BF16) {
        asm volatile("s_waitcnt vmcnt(2)" ::: "memory");
        A_WRITE(va, nxt);
      }
      asm volatile("s_waitcnt vmcnt(0) lgkmcnt(0)" ::: "memory");
      __builtin_amdgcn_s_barrier();
    }
  }

  if (OUT_MODE == 2) {
    unsigned short* sc = smem;
    const int wr4 = wr >> 2;
#pragma unroll
    for (int m = 0; m < 4; ++m)
#pragma unroll
      for (int n = 0; n < 4; ++n) {
        int col = wc + n * 16 + r;
        float bv = bias[bcol + col];
        int sl = wr4 + m * 4 + g;                       // local key 0..31
        int pp = ((sl >> 2) & 3) * 8 + ((sl >> 4) & 1) * 4 + (sl & 3);  // sigma
#pragma unroll
        for (int rr = 0; rr < 4; ++rr) {
          int c = (rr * 4 + (pp >> 3)) ^ (col & 7);
          sc[col * 128 + c * 8 + (pp & 7)] = f2bf((acc[m][n][rr] + bv) * scale);
        }
      }
    asm volatile("s_waitcnt lgkmcnt(0)" ::: "memory");
    __builtin_amdgcn_s_barrier();
    unsigned short* VT = (unsigned short*)Outp;
#pragma unroll
    for (int i2 = 0; i2 < 2; ++i2) {
      int q = tid * 2 + i2;
      int col = q >> 2, bb = q & 3;
      int gcol = bcol + col, hh = gcol >> 6, nh = gcol & 63;
      size_t gbase = (((size_t)bb * H + hh) * NH + nh) * SL + (brow >> 2);
#pragma unroll
      for (int j = 0; j < 4; ++j) {
        short8 v = *reinterpret_cast<const short8*>(
            &sc[col * 128 + (((bb * 4 + j) ^ (col & 7)) * 8)]);
        *reinterpret_cast<short8*>(&VT[gbase + j * 8]) = v;
      }
    }
  } else {
#pragma unroll
    for (int m = 0; m < 4; ++m)
#pragma unroll
      for (int n = 0; n < 4; ++n) {
        int gcol = bcol + wc + n * 16 + r;
        float bv = bias[gcol];
#pragma unroll
        for (int rr = 0; rr < 4; ++rr) {
          int grow = brow + wr + m * 16 + g * 4 + rr;
          float val = (acc[m][n][rr] + bv) * scale;
          if (OUT_MODE == 0)
            ((float*)Outp)[(size_t)grow * D + gcol] = val;
          else
            ((unsigned short*)Outp)[(size_t)grow * D + gcol] = f2bf(val);
        }
      }
  }
}

__global__ __launch_bounds__(256, 2) void qkv_gemm(
    const float* __restrict__ x0, const float* __restrict__ x1, const float* __restrict__ x2,
    const unsigned short* __restrict__ wtb,
    const float* __restrict__ b0, const float* __restrict__ b1, const float* __restrict__ b2,
    unsigned short* __restrict__ q_out, unsigned short* __restrict__ k_out,
    unsigned short* __restrict__ vt_out) {
  __shared__ __align__(16) unsigned short smem[2 * 16384];
  const int bid = blockIdx.x;
  const int sgrp = bid >> 5, idx = bid & 31;
  const int xcd = idx & 7, y = idx >> 3;
  const int flat = sgrp * 8 + xcd;           // 0..191
  const int x = flat & 63, z = flat >> 6;    // z in 0..2
  const float* X = z == 0 ? x0 : (z == 1 ? x1 : x2);
  const unsigned short* WT = wtb + (size_t)z * D * D;
  const float* B = z == 0 ? b0 : (z == 1 ? b1 : b2);
  float scale = (z == 0) ? SCALE * LOG2E : 1.0f;
  if (z == 2)
    gemm_bt_body<false, 2>(X, WT, B, vt_out, scale, smem, x, y);
  else
    gemm_bt_body<false, 1>(X, WT, B, z == 0 ? q_out : k_out, scale, smem, x, y);
}

__global__ __launch_bounds__(256, 2) void gemm_oproj(
    const unsigned short* __restrict__ A, const unsigned short* __restrict__ WT,
    const float* __restrict__ B, float* __restrict__ Outp) {
  __shared__ __align__(16) unsigned short smem[2 * 16384];
  const int bid = blockIdx.x;
  const int sgrp = bid >> 5, idx = bid & 31;
  const int xcd = idx & 7, y = idx >> 3;
  const int x = sgrp * 8 + xcd;              // 0..63
  gemm_bt_body<true, 0>(A, WT, B, Outp, 1.0f, smem, x, y);
}

// ---------------------------------------------------------------------------
// Flash attention v8: v7 + SPLIT-KV for qt>=16 (critical path 32 -> 16
// phases; merge via online-softmax algebra in a combine pass). Grid 1536 =
// 32 bh x 48 slots: slots 0..31 = split halves of qt 31..16 (longest first),
// slots 32..47 = single tiles qt 15..0. Split partials (normalized O + m,l)
// go to d_out scratch; single tiles write qb directly (O aliases Q is safe:
// split blocks never write qb).
// ---------------------------------------------------------------------------
__global__ __launch_bounds__(256, 3) void flash_attn(
    const unsigned short* __restrict__ Q, const unsigned short* __restrict__ K,
    const unsigned short* __restrict__ Vt, unsigned short* __restrict__ O,
    unsigned short* __restrict__ part) {
  __shared__ __align__(16) unsigned short k_lds[3][64 * 64];
  __shared__ __align__(16) unsigned short v_lds[3][64 * 64];

  const int bid = blockIdx.x;
  const int idx = bid & 31;
  const int grp = idx & 7;              // XCD group
  const int bh = grp * 4 + (idx >> 3);  // 4 (b,h) per XCD group
  const int b = bh >> 3, h = bh & 7;
  const int s = bid >> 5;               // 0..47
  int qt, kt_lo, kt_hi, sid;
  if (s < 32) {                         // split halves, qt 31..16
    qt = 31 - (s >> 1);
    sid = s & 1;
    int lo = (qt + 1) >> 1;
    kt_lo = sid ? lo : 0;
    kt_hi = sid ? qt : lo - 1;
  } else {                              // single, qt 15..0
    qt = 47 - s;
    sid = -1;
    kt_lo = 0; kt_hi = qt;
  }
  const int q0 = qt * 64;

  const int tid = threadIdx.x;
  const int w = tid >> 6, lane = tid & 63;
  const int r = lane & 15, g = lane >> 4;
  const int swz = (r & 7) << 3;

  const unsigned short* Qb = Q + (size_t)b * D + h * NH;
  const unsigned short* Kb = K + (size_t)b * D + h * NH;
  const unsigned short* Vb = Vt + ((size_t)(b * H + h) * NH) * SL;
  unsigned short* Ob = O + (size_t)b * D + h * NH;

  auto STAGE = [&](int kt, int bsel) {
    unsigned short* kl = &k_lds[bsel][0];
    unsigned short* vl = &v_lds[bsel][0];
#pragma unroll
    for (int j = 0; j < 2; ++j) {
      int c = j * 256 + tid;
      int row = c >> 3, c8 = (c & 7) ^ (row & 7);
      gl16(&Kb[(size_t)(kt * 64 + row) * (BS * D) + c8 * 8], &kl[c * 8]);
      gl16(&Vb[(size_t)row * SL + kt * 64 + c8 * 8], &vl[c * 8]);
    }
  };

  STAGE(kt_lo, 0);
  if (kt_lo + 1 <= kt_hi) STAGE(kt_lo + 1, 1);

  short8 qf[2];
#pragma unroll
  for (int kk = 0; kk < 2; ++kk)
    qf[kk] = *reinterpret_cast<const short8*>(
        &Qb[(size_t)(q0 + w * 16 + r) * (BS * D) + kk * 32 + g * 8]);

  f32x4 oa[4];
#pragma unroll
  for (int n = 0; n < 4; ++n) oa[n] = f32x4{0.f, 0.f, 0.f, 0.f};
  float mr = -1e30f, lrp = 0.f;

  int bsel = 0;
  for (int kt = kt_lo; kt <= kt_hi; ++kt) {
    if (kt < kt_hi)
      asm volatile("s_waitcnt vmcnt(8)" ::: "memory");
    else
      asm volatile("s_waitcnt vmcnt(0)" ::: "memory");
    __builtin_amdgcn_s_barrier();
    __builtin_amdgcn_sched_barrier(0);
    if (kt + 2 <= kt_hi) {
      int nb = bsel + 2; if (nb >= 3) nb -= 3;
      STAGE(kt + 2, nb);
    }

    const unsigned short* kl = &k_lds[bsel][0];
    const unsigned short* vl = &v_lds[bsel][0];
    short8 kf[2][4];
#pragma unroll
    for (int kk = 0; kk < 2; ++kk)
#pragma unroll
      for (int n = 0; n < 4; ++n)
        kf[kk][n] = *reinterpret_cast<const short8*>(
            &kl[(n * 16 + r) * 64 + ((kk * 32 + g * 8) ^ swz)]);

    f32x4 sv[4];
#pragma unroll
    for (int n = 0; n < 4; ++n) sv[n] = f32x4{0.f, 0.f, 0.f, 0.f};
#pragma unroll
    for (int kk = 0; kk < 2; ++kk)
#pragma unroll
      for (int n = 0; n < 4; ++n)
        sv[n] = __builtin_amdgcn_mfma_f32_16x16x32_bf16(kf[kk][n], qf[kk], sv[n], 0, 0, 0);

    short8 vt[2][4];
#pragma unroll
    for (int kk = 0; kk < 2; ++kk)
#pragma unroll
      for (int n = 0; n < 4; ++n)
        vt[kk][n] = *reinterpret_cast<const short8*>(
            &vl[(n * 16 + r) * 64 + ((kk * 32 + g * 8) ^ swz)]);

    if (kt == qt) {
      int qrow = q0 + w * 16 + r;
#pragma unroll
      for (int n = 0; n < 4; ++n)
#pragma unroll
        for (int rr = 0; rr < 4; ++rr)
          if (kt * 64 + n * 16 + g * 4 + rr > qrow) sv[n][rr] = -1e30f;
    }

    float t0 = fmaxf(fmaxf(sv[0][0], sv[0][1]), sv[0][2]);
    float t1 = fmaxf(fmaxf(sv[0][3], sv[1][0]), sv[1][1]);
    float t2 = fmaxf(fmaxf(sv[1][2], sv[1][3]), sv[2][0]);
    float t3 = fmaxf(fmaxf(sv[2][1], sv[2][2]), sv[2][3]);
    float t4 = fmaxf(fmaxf(sv[3][0], sv[3][1]), sv[3][2]);
    float mxl = fmaxf(fmaxf(fmaxf(t0, t1), fmaxf(t2, t3)), fmaxf(t4, sv[3][3]));
    bool need = __any(mxl > mr + 8.f);
    float mold = mr;
    float mnew = mold;
    if (need) {
      float mx = fmaxf(mxl, __shfl_xor(mxl, 16));
      mx = fmaxf(mx, __shfl_xor(mx, 32));
      mnew = fmaxf(mold, mx);
    }
#pragma unroll
    for (int n = 0; n < 4; ++n)
#pragma unroll
      for (int rr = 0; rr < 4; ++rr)
        sv[n][rr] = fast_exp2(sv[n][rr] - mnew);
    float a0 = (sv[0][0] + sv[0][1]) + (sv[0][2] + sv[0][3]);
    float a1 = (sv[1][0] + sv[1][1]) + (sv[1][2] + sv[1][3]);
    float a2 = (sv[2][0] + sv[2][1]) + (sv[2][2] + sv[2][3]);
    float a3 = (sv[3][0] + sv[3][1]) + (sv[3][2] + sv[3][3]);
    float psl = (a0 + a1) + (a2 + a3);
    if (need) {
      float sf = fast_exp2(mold - mnew);
      mr = mnew;
      lrp = lrp * sf + psl;
#pragma unroll
      for (int n = 0; n < 4; ++n) oa[n] *= sf;
    } else {
      lrp += psl;
    }

    short8 pf[2];
#pragma unroll
    for (int kk = 0; kk < 2; ++kk) {
      union { unsigned u[4]; short8 s8; } P;
      P.u[0] = cvt_pk_bf16(sv[2 * kk][0], sv[2 * kk][1]);
      P.u[1] = cvt_pk_bf16(sv[2 * kk][2], sv[2 * kk][3]);
      P.u[2] = cvt_pk_bf16(sv[2 * kk + 1][0], sv[2 * kk + 1][1]);
      P.u[3] = cvt_pk_bf16(sv[2 * kk + 1][2], sv[2 * kk + 1][3]);
      pf[kk] = P.s8;
    }

#pragma unroll
    for (int kk = 0; kk < 2; ++kk)
#pragma unroll
      for (int n = 0; n < 4; ++n)
        oa[n] = __builtin_amdgcn_mfma_f32_16x16x32_bf16(vt[kk][n], pf[kk], oa[n], 0, 0, 0);

    ++bsel; if (bsel >= 3) bsel = 0;
  }

  // ---- epilogue: normalize; single -> qb; split -> partials in d_out ----
  __syncthreads();
  {
    unsigned short* pw = &k_lds[0][0] + w * 2048;
    float lr = lrp + __shfl_xor(lrp, 16);
    lr += __shfl_xor(lr, 32);
    float inv = 1.0f / lr;
#pragma unroll
    for (int n = 0; n < 4; ++n) {
      uint2v pk;
      pk.x = cvt_pk_bf16(oa[n][0] * inv, oa[n][1] * inv);
      pk.y = cvt_pk_bf16(oa[n][2] * inv, oa[n][3] * inv);
      *reinterpret_cast<uint2v*>(&pw[r * 64 + ((n * 16 + g * 4) ^ swz)]) = pk;
    }
    asm volatile("s_waitcnt lgkmcnt(0)" ::: "memory");
    __builtin_amdgcn_sched_barrier(0);
    if (sid >= 0) {
      const int pidx = bh * 16 + (qt - 16);           // 0..511
      float* ml = (float*)(part + 2 * 512 * 4096);
      if (lane < 16) {                                // g == 0: one lane per row
        int row16 = w * 16 + r;
        ml[((size_t)sid * 512 + pidx) * 128 + row16 * 2 + 0] = mr;
        ml[((size_t)sid * 512 + pidx) * 128 + row16 * 2 + 1] = lr;
      }
      unsigned short* op = part + ((size_t)sid * 512 + pidx) * 4096;
#pragma unroll
      for (int i2 = 0; i2 < 2; ++i2) {
        int c = i2 * 64 + lane;
        int row = c >> 3, c8 = c & 7;
        short8 v = *reinterpret_cast<const short8*>(&pw[row * 64 + c8 * 8]);
        *reinterpret_cast<short8*>(
            &op[(w * 16 + row) * 64 + ((c8 ^ (row & 7)) * 8)]) = v;
      }
    } else {
#pragma unroll
      for (int i2 = 0; i2 < 2; ++i2) {
        int c = i2 * 64 + lane;
        int row = c >> 3, c8 = c & 7;
        short8 v = *reinterpret_cast<const short8*>(&pw[row * 64 + c8 * 8]);
        *reinterpret_cast<short8*>(
            &Ob[(size_t)(q0 + w * 16 + row) * (BS * D) + ((c8 ^ (row & 7)) * 8)]) = v;
      }
    }
  }
}

// ---------------------------------------------------------------------------
// combine: merge the two normalized partials of each split tile (qt>=16)
// via online-softmax algebra and write the final O into qb.
// Grid 512: cid = bh*16 + (qt-16). 256 threads: row = tid>>2, 16-col strip.
// ---------------------------------------------------------------------------
__global__ __launch_bounds__(256) void combine(
    const unsigned short* __restrict__ part, unsigned short* __restrict__ Oq) {
  const float* ml = (const float*)(part + 2 * 512 * 4096);
  const int cid = blockIdx.x;
  const int bh = cid >> 4, qtm = cid & 15;
  const int b = bh >> 3, h = bh & 7;
  const int q0 = (16 + qtm) * 64;
  const int tid = threadIdx.x;
  const int row = tid >> 2, cq = (tid & 3) * 16;

  const size_t p = (size_t)cid;
  float m0 = ml[p * 128 + row * 2 + 0];
  float l0 = ml[p * 128 + row * 2 + 1];
  float m1 = ml[(512 + p) * 128 + row * 2 + 0];
  float l1 = ml[(512 + p) * 128 + row * 2 + 1];
  float M = fmaxf(m0, m1);
  float w0 = fast_exp2(m0 - M) * l0;
  float w1 = fast_exp2(m1 - M) * l1;
  float inv = 1.0f / (w0 + w1);
  float c0 = w0 * inv, c1 = w1 * inv;

  const unsigned short* s0 = part + p * 4096 + row * 64 + cq;
  const unsigned short* s1 = part + (512 + p) * 4096 + row * 64 + cq;
  unsigned short* dst = Oq + (size_t)(q0 + row) * (BS * D) + b * D + h * NH + cq;
#pragma unroll
  for (int half = 0; half < 2; ++half) {
    union { unsigned short u[8]; short8 s8; } a, bb, o;
    a.s8 = *reinterpret_cast<const short8*>(s0 + half * 8);
    bb.s8 = *reinterpret_cast<const short8*>(s1 + half * 8);
#pragma unroll
    for (int j = 0; j < 8; ++j)
      o.u[j] = f2bf(c0 * bf2f(a.u[j]) + c1 * bf2f(bb.u[j]));
    *reinterpret_cast<short8*>(dst + half * 8) = o.s8;
  }
}

// ---------------------------------------------------------------------------
extern "C" void kernel_launch(void* const* d_in, const int* in_sizes, int n_in,
                              void* d_out, int out_size, void* d_ws, size_t ws_size,
                              hipStream_t stream) {
  const float* x  = (const float*)d_in[0];
  const float* kx = (const float*)d_in[1];
  const float* vx = (const float*)d_in[2];
  const float* Wq = (const float*)d_in[3];
  const float* bq = (const float*)d_in[4];
  const float* Wk = (const float*)d_in[5];
  const float* bk = (const float*)d_in[6];
  const float* Wv = (const float*)d_in[7];
  const float* bv = (const float*)d_in[8];
  const float* Wo = (const float*)d_in[9];
  const float* bo = (const float*)d_in[10];

  // ws (bf16), 27.3 MB: qb (attn-out aliases) | kb | vtb | wtb.
  // Split-tile partials + (m,l) live in d_out (dead until oproj): 8.5 MB.
  unsigned short* ws = (unsigned short*)d_ws;
  unsigned short* qb  = ws;
  unsigned short* kb  = ws + (size_t)M_ROWS * D;
  unsigned short* vtb = ws + (size_t)M_ROWS * D * 2;
  unsigned short* wtb = ws + (size_t)M_ROWS * D * 3;
  unsigned short* part = (unsigned short*)d_out;

  prep_wt<<<dim3(256), dim3(256), 0, stream>>>(Wq, Wk, Wv, Wo, wtb);
  qkv_gemm<<<dim3(768), dim3(256), 0, stream>>>(x, kx, vx, wtb, bq, bk, bv,
                                                qb, kb, vtb);
  flash_attn<<<dim3(1536), dim3(256), 0, stream>>>(qb, kb, vtb, qb, part);
  combine<<<dim3(512), dim3(256), 0, stream>>>(part, qb);
  gemm_oproj<<<dim3(256), dim3(256), 0, stream>>>(qb, wtb + (size_t)3 * D * D,
                                                  bo, (float*)d_out);
}